// Round 2
// 369.969 us; speedup vs baseline: 1.0232x; 1.0232x over previous
//
#include <hip/hip_runtime.h>
#include <hip/hip_bf16.h>
#include <math.h>

// ---------------------------------------------------------------------------
// PatentCitationMoEModule — MI355X implementation, round 8 (resubmit; round-1
// bench failed at container acquire — infra, not kernel).
//  Round 7 (378.6 us) plus:
//   - score_tab_kernel ELIMINATED: scores are computed inside xbar from the
//     same gathered embedding rows (held in registers across score -> softmax
//     -> weighted sum). Kills the 51 MB ipc_emb stream + tab round-trip + one
//     dispatch. Masked rows are never loaded (mask==0 <=> attn==0).
//   - pool_kernel: waves now split the d(K)-dimension instead of rows, so Wv
//     is read once per block: 268 MB -> 64 MB of L2 traffic.
//  Fixed harness overhead (ws poison fill ~40us + d_in restore) untouched.
// ---------------------------------------------------------------------------

#define LN_EPS 1e-5f

typedef __bf16 bf16_t;
typedef __bf16 bf16x8 __attribute__((ext_vector_type(8)));
typedef float f32x4 __attribute__((ext_vector_type(4)));

struct f4x2 { float4 a, b; };
__device__ __forceinline__ f4x2 ldA8(const float* p) {
  f4x2 v; v.a = *(const float4*)p; v.b = *(const float4*)(p + 4); return v;
}
__device__ __forceinline__ bf16x8 cvt8(const f4x2& v) {
  bf16x8 o;
  o[0] = (bf16_t)v.a.x; o[1] = (bf16_t)v.a.y; o[2] = (bf16_t)v.a.z; o[3] = (bf16_t)v.a.w;
  o[4] = (bf16_t)v.b.x; o[5] = (bf16_t)v.b.y; o[6] = (bf16_t)v.b.z; o[7] = (bf16_t)v.b.w;
  return o;
}

// -------- merged: weight transpose->FT layout (z<24) + prep_kq (z==24) -----
// FT-B: frag (nt,kt) = 64 lanes x 8 bf16; lane holds n=nt*16+(lane&15),
// k = kt*32+(lane>>4)*8 .. +7.  Flat elem offset: ((nt*(K/32)+kt)*64+lane)*8.
__global__ __launch_bounds__(256)
void transpose_prep(const float* __restrict__ W1, const float* __restrict__ W2,
                    const float* __restrict__ W3, bf16_t* __restrict__ B1,
                    bf16_t* __restrict__ B2, bf16_t* __restrict__ B3,
                    const float* __restrict__ Wq, const float* __restrict__ bq,
                    const float* __restrict__ Wk, const float* __restrict__ bk,
                    const float* __restrict__ gc, float* __restrict__ kq_out) {
  __shared__ float tile[64][65];
  const int z = blockIdx.z;
  if (z == 24) {
    // ---- prep_kq path: 32 active blocks (y<2), bi = y*16+x ----
    if (blockIdx.y >= 2) return;
    float* q = &tile[0][0];        // alias LDS: q[0..255], red[256..259]
    float* red = &tile[0][0] + 256;
    const int t = threadIdx.x, bi = blockIdx.y * 16 + blockIdx.x;
    float s = bq[t];
    for (int d = 0; d < 256; d++) s += gc[d] * Wq[d * 256 + t];
    q[t] = s;
    __syncthreads();
    const int rl = t >> 5, sl = t & 31;
    const int r = bi * 8 + rl;
    float p = 0.f;
#pragma unroll
    for (int i = 0; i < 8; i++) { const int d = sl + 32 * i; p += Wk[r * 256 + d] * q[d]; }
#pragma unroll
    for (int o = 16; o > 0; o >>= 1) p += __shfl_down(p, o, 32);
    if (sl == 0) kq_out[r] = p;
    if (bi == 0) {
      float z2 = q[t] * bk[t];
      const int lane = t & 63, wave = t >> 6;
#pragma unroll
      for (int o = 32; o > 0; o >>= 1) z2 += __shfl_down(z2, o);
      if (lane == 0) red[wave] = z2;
      __syncthreads();
      if (t == 0) kq_out[256] = red[0] + red[1] + red[2] + red[3];
    }
    return;
  }
  // ---- transpose path ----
  const float* W; bf16_t* Bft; int K, N, e;
  if (z < 8)       { W = W1; Bft = B1; K = 512;  N = 1024; e = z; }
  else if (z < 16) { W = W2; Bft = B2; K = 1024; N = 1024; e = z - 8; }
  else             { W = W3; Bft = B3; K = 1024; N = 512;  e = z - 16; }
  const int n0 = blockIdx.x * 64, k0 = blockIdx.y * 64;
  if (n0 >= N || k0 >= K) return;
  const float* Wp = W + (size_t)e * K * N;
  bf16_t* Bp = Bft + (size_t)e * N * K;
  const int tq = threadIdx.x & 15, th = threadIdx.x >> 4;  // 16 x 16
#pragma unroll
  for (int i = 0; i < 4; i++) {
    const int row = th + 16 * i;  // k-dim
    *(float4*)&tile[row][tq * 4] = *(const float4*)(Wp + (size_t)(k0 + row) * N + n0 + tq * 4);
  }
  __syncthreads();
  const int lane = threadIdx.x & 63, sub = threadIdx.x >> 6;
  const int nk = K >> 5;
#pragma unroll
  for (int it = 0; it < 2; it++) {
    const int fid = sub + it * 4;            // 8 frag-tiles in a 64x64 tile
    const int ntl = fid & 3, ktl = fid >> 2;
    const int n_l = ntl * 16 + (lane & 15);
    const int k_l = ktl * 32 + (lane >> 4) * 8;
    bf16x8 o;
#pragma unroll
    for (int j = 0; j < 8; j++) o[j] = (bf16_t)tile[k_l + j][n_l];
    const size_t idx = ((((size_t)(n0 >> 4) + ntl) * nk + (k0 >> 5) + ktl) * 64 + lane) * 8;
    *(bf16x8*)(Bp + idx) = o;
  }
}

// ------ xbar: fused row-gather + inline scores + softmax + weighted sum -----
// score[b,l] = x[b,l] . kq + (q.bk), x = ipc_emb[ii] + role_emb[ri].
// Rows are gathered once into registers (16 rows/wave), reused for score and
// for the attn-weighted pooling. Masked rows are never loaded (attn == 0).
__global__ __launch_bounds__(256)
void xbar_kernel(const int* __restrict__ ipc_idx, const int* __restrict__ role_idx,
                 const int* __restrict__ maskp,
                 const float* __restrict__ ipc_emb, const float* __restrict__ role_emb,
                 const float* __restrict__ kq_qbk, float* __restrict__ xbar_g) {
  const int b = blockIdx.x;
  __shared__ float scores_s[64];
  __shared__ float attn_s[64];
  __shared__ __align__(16) float part[4][256];
  const int t = threadIdx.x, wave = t >> 6, lane = t & 63;
  const float4 kq = *(const float4*)(kq_qbk + lane * 4);
  const float qbk = kq_qbk[256];
  const int rbase = b * 64 + wave * 16;
  // phase 1: gather this wave's 16 rows (unmasked only) into registers
  float4 x[16];
  int mk[16];
#pragma unroll
  for (int i = 0; i < 16; i++) {
    mk[i] = maskp[rbase + i];
    if (mk[i] != 0) {
      const int ii = ipc_idx[rbase + i], ri = role_idx[rbase + i];
      const float4 xe = *(const float4*)(ipc_emb + (size_t)ii * 256 + lane * 4);
      const float4 re = *(const float4*)(role_emb + (size_t)ri * 256 + lane * 4);
      x[i] = make_float4(xe.x + re.x, xe.y + re.y, xe.z + re.z, xe.w + re.w);
    } else {
      x[i] = make_float4(0.f, 0.f, 0.f, 0.f);
    }
  }
  // phase 2: scores (full-wave dot with kq)
#pragma unroll
  for (int i = 0; i < 16; i++) {
    float s;
    if (mk[i] != 0) {
      s = x[i].x * kq.x + x[i].y * kq.y + x[i].z * kq.z + x[i].w * kq.w;
#pragma unroll
      for (int o = 32; o > 0; o >>= 1) s += __shfl_xor(s, o);
      s += qbk;
    } else {
      s = -1e9f;
    }
    if (lane == 0) scores_s[wave * 16 + i] = s;
  }
  __syncthreads();
  // phase 3: softmax over the 64 scores (wave 0)
  if (wave == 0) {
    const float sv = scores_s[lane];
    float m = sv;
#pragma unroll
    for (int o = 32; o > 0; o >>= 1) m = fmaxf(m, __shfl_xor(m, o));
    const float ev = expf(sv - m);
    float sum = ev;
#pragma unroll
    for (int o = 32; o > 0; o >>= 1) sum += __shfl_xor(sum, o);
    attn_s[lane] = ev / sum;
  }
  __syncthreads();
  // phase 4: attn-weighted sum from registers
  float p0 = 0.f, p1 = 0.f, p2 = 0.f, p3 = 0.f;
#pragma unroll
  for (int i = 0; i < 16; i++) {
    const float a = attn_s[wave * 16 + i];   // 0 exactly for masked rows
    p0 += a * x[i].x; p1 += a * x[i].y; p2 += a * x[i].z; p3 += a * x[i].w;
  }
  *(float4*)&part[wave][lane * 4] = make_float4(p0, p1, p2, p3);
  __syncthreads();
  xbar_g[(size_t)b * 256 + t] = part[0][t] + part[1][t] + part[2][t] + part[3][t];
}

// ------------- pool: pooled = xbar@Wv + bv, LN, gate, top2 ------------------
// Waves split the d(K)-range so Wv is read once per block (64 MB total).
__global__ __launch_bounds__(256)
void pool_kernel(const float* __restrict__ xbar_g, const float* __restrict__ Wv,
                 const float* __restrict__ bvec,
                 const float* __restrict__ ln_g, const float* __restrict__ ln_b,
                 const float* __restrict__ gate_W, const float* __restrict__ gate_b,
                 const float* __restrict__ expert_biases,
                 float* __restrict__ out_idx_f, int* __restrict__ ws_idx,
                 float* __restrict__ ws_gw) {
  const int rb = blockIdx.x * 8;
  __shared__ __align__(16) float xs[8][256];       // 8 input rows
  __shared__ __align__(16) float pp[4][8][256];    // per-wave d-partials
  const int t = threadIdx.x, wave = t >> 6, lane = t & 63;
  for (int i = t; i < 512; i += 256)
    ((float4*)xs)[i] = ((const float4*)(xbar_g + (size_t)rb * 256))[i];
  __syncthreads();
  f32x4 acc[8];
#pragma unroll
  for (int r = 0; r < 8; r++) acc[r] = (f32x4){0.f, 0.f, 0.f, 0.f};
  const int dbase = wave * 64;
  for (int dd = 0; dd < 64; dd += 4) {
    float4 xr[8];
#pragma unroll
    for (int r = 0; r < 8; r++) xr[r] = *(const float4*)&xs[r][dbase + dd];  // broadcast
#pragma unroll
    for (int j = 0; j < 4; j++) {
      const float4 wv = *(const float4*)(Wv + (size_t)(dbase + dd + j) * 256 + lane * 4);
#pragma unroll
      for (int r = 0; r < 8; r++) {
        const float xv = (&xr[r].x)[j];
        acc[r][0] += xv * wv.x; acc[r][1] += xv * wv.y;
        acc[r][2] += xv * wv.z; acc[r][3] += xv * wv.w;
      }
    }
  }
#pragma unroll
  for (int r = 0; r < 8; r++) *(f32x4*)&pp[wave][r][lane * 4] = acc[r];
  __syncthreads();
  const float4 bvv = *(const float4*)(bvec + lane * 4);
  const float4 lg = *(const float4*)(ln_g + lane * 4);
  const float4 lb = *(const float4*)(ln_b + lane * 4);
#pragma unroll
  for (int rr = 0; rr < 2; rr++) {
    const int r = wave * 2 + rr;
    f32x4 v = *(const f32x4*)&pp[0][r][lane * 4];
#pragma unroll
    for (int w2 = 1; w2 < 4; w2++) {
      const f32x4 qv = *(const f32x4*)&pp[w2][r][lane * 4];
      v[0] += qv[0]; v[1] += qv[1]; v[2] += qv[2]; v[3] += qv[3];
    }
    v[0] += bvv.x; v[1] += bvv.y; v[2] += bvv.z; v[3] += bvv.w;
    float s1 = v[0] + v[1] + v[2] + v[3];
#pragma unroll
    for (int o = 32; o > 0; o >>= 1) s1 += __shfl_xor(s1, o);
    const float mu = s1 * (1.f / 256.f);
    const float4 df = make_float4(v[0] - mu, v[1] - mu, v[2] - mu, v[3] - mu);
    float s2 = df.x * df.x + df.y * df.y + df.z * df.z + df.w * df.w;
#pragma unroll
    for (int o = 32; o > 0; o >>= 1) s2 += __shfl_xor(s2, o);
    const float inv = 1.f / sqrtf(s2 * (1.f / 256.f) + LN_EPS);
    f32x4 rv;
    rv[0] = df.x * inv * lg.x + lb.x; rv[1] = df.y * inv * lg.y + lb.y;
    rv[2] = df.z * inv * lg.z + lb.z; rv[3] = df.w * inv * lg.w + lb.w;
    f32x4 pa = {0.f, 0.f, 0.f, 0.f}, pb = {0.f, 0.f, 0.f, 0.f};
#pragma unroll
    for (int k = 0; k < 4; k++) {
      const int d = lane * 4 + k;
      const f32x4 g0 = *(const f32x4*)(gate_W + d * 8);
      const f32x4 g1 = *(const f32x4*)(gate_W + d * 8 + 4);
      pa += rv[k] * g0;
      pb += rv[k] * g1;
    }
#pragma unroll
    for (int o = 32; o > 0; o >>= 1) {
      pa[0] += __shfl_down(pa[0], o); pa[1] += __shfl_down(pa[1], o);
      pa[2] += __shfl_down(pa[2], o); pa[3] += __shfl_down(pa[3], o);
      pb[0] += __shfl_down(pb[0], o); pb[1] += __shfl_down(pb[1], o);
      pb[2] += __shfl_down(pb[2], o); pb[3] += __shfl_down(pb[3], o);
    }
    if (lane == 0) {
      float aff[8];
#pragma unroll
      for (int j = 0; j < 4; j++) { aff[j] = pa[j] + gate_b[j]; aff[4 + j] = pb[j] + gate_b[4 + j]; }
      float b0 = -1e30f; int i0 = 0;
#pragma unroll
      for (int j = 0; j < 8; j++) {
        const float s = aff[j] + expert_biases[j];
        if (s > b0) { b0 = s; i0 = j; }
      }
      float b1v = -1e30f; int i1 = 0;
#pragma unroll
      for (int j = 0; j < 8; j++) {
        const float s = aff[j] + expert_biases[j];
        if (j != i0 && s > b1v) { b1v = s; i1 = j; }
      }
      const float a0 = aff[i0], a1 = aff[i1];
      const float m = fmaxf(a0, a1);
      const float e0 = expf(a0 - m), e1 = expf(a1 - m);
      const float invs = 1.f / (e0 + e1);
      const int bg = rb + r;
      ws_idx[bg * 2] = i0; ws_idx[bg * 2 + 1] = i1;
      ws_gw[bg * 2] = e0 * invs; ws_gw[bg * 2 + 1] = e1 * invs;
      out_idx_f[bg * 2] = (float)i0; out_idx_f[bg * 2 + 1] = (float)i1;
    }
  }
}

// ------------------------ pack (64-aligned segments) ------------------------
__global__ __launch_bounds__(256)
void pack_kernel(const int* __restrict__ ws_idx, int* __restrict__ list_token,
                 int* __restrict__ a_of, int* __restrict__ offsets_g) {
  __shared__ int cnt[8]; __shared__ int off[9]; __shared__ int fill[8];
  const int t = threadIdx.x;
  if (t < 8) cnt[t] = 0;
  __syncthreads();
  for (int a = t; a < 4096; a += 256) atomicAdd(&cnt[ws_idx[a]], 1);
  __syncthreads();
  if (t == 0) {
    off[0] = 0;
    for (int e = 0; e < 8; e++) off[e + 1] = off[e] + ((cnt[e] + 63) & ~63);
  }
  __syncthreads();
  if (t < 8) fill[t] = off[t];
  if (t < 9) offsets_g[t] = off[t];
  for (int a = t; a < 4608; a += 256) list_token[a] = 0;  // pad rows -> token 0
  __syncthreads();
  for (int a = t; a < 4096; a += 256) {
    const int e = ws_idx[a];
    const int pos = atomicAdd(&fill[e], 1);
    list_token[pos] = a >> 1;
    a_of[a] = pos;
  }
}

// --------- GEMM-1: fused bib gather (fp32->bf16 in-register), FT-B ----------
// C[rows,NT] = cvt_bf16(bib[list_token[row]]) @ B1_e ; K=512.
template <int NT, bool RELU>
__global__ __launch_bounds__(256)
void expert_gemm_g1(const float* __restrict__ bib, const int* __restrict__ list_token,
                    const bf16_t* __restrict__ Bft, const float* __restrict__ bias,
                    bf16_t* __restrict__ C, const int* __restrict__ offsets) {
  constexpr int K = 512, nk = K / 32;
  const int e = blockIdx.z;
  const int seg_hi = offsets[e + 1];
  const int blk_row = offsets[e] + blockIdx.y * 128;
  if (blk_row >= seg_hi) return;
  const int wave = threadIdx.x >> 6, lane = threadIdx.x & 63;
  const int row0 = blk_row + wave * 32;
  if (row0 >= seg_hi) return;
  const int n0 = blockIdx.x * 64;
  const int tok0 = list_token[row0 + (lane & 15)];
  const int tok1 = list_token[row0 + 16 + (lane & 15)];
  const float* Ap0 = bib + (size_t)tok0 * 512 + (lane >> 4) * 8;
  const float* Ap1 = bib + (size_t)tok1 * 512 + (lane >> 4) * 8;
  const bf16_t* Bp = Bft + (size_t)e * NT * K + ((size_t)(n0 >> 4) * nk * 512 + lane * 8);
  f32x4 acc[2][4];
#pragma unroll
  for (int i = 0; i < 2; i++)
#pragma unroll
    for (int j = 0; j < 4; j++) acc[i][j] = (f32x4){0.f, 0.f, 0.f, 0.f};
  f4x2 aS[2][2]; bf16x8 bX[2][4];
  aS[0][0] = ldA8(Ap0); aS[0][1] = ldA8(Ap1);
#pragma unroll
  for (int ni = 0; ni < 4; ni++) bX[0][ni] = *(const bf16x8*)(Bp + (size_t)ni * nk * 512);
#pragma unroll
  for (int kt = 0; kt < nk; kt++) {
    const int cur = kt & 1, nxt = cur ^ 1;
    if (kt + 1 < nk) {
      aS[nxt][0] = ldA8(Ap0 + (kt + 1) * 32);
      aS[nxt][1] = ldA8(Ap1 + (kt + 1) * 32);
#pragma unroll
      for (int ni = 0; ni < 4; ni++)
        bX[nxt][ni] = *(const bf16x8*)(Bp + ((size_t)ni * nk + kt + 1) * 512);
    }
    const bf16x8 a0 = cvt8(aS[cur][0]), a1 = cvt8(aS[cur][1]);
#pragma unroll
    for (int ni = 0; ni < 4; ni++) {
      acc[0][ni] = __builtin_amdgcn_mfma_f32_16x16x32_bf16(a0, bX[cur][ni], acc[0][ni], 0, 0, 0);
      acc[1][ni] = __builtin_amdgcn_mfma_f32_16x16x32_bf16(a1, bX[cur][ni], acc[1][ni], 0, 0, 0);
    }
  }
  const int fr = lane & 15, q = lane >> 4;
#pragma unroll
  for (int ni = 0; ni < 4; ni++) {
    const int col = n0 + ni * 16 + fr;
    const float bv = bias[e * NT + col];
#pragma unroll
    for (int mi = 0; mi < 2; mi++) {
#pragma unroll
      for (int r = 0; r < 4; r++) {
        const int row = row0 + mi * 16 + q * 4 + r;
        float v = acc[mi][ni][r] + bv;
        if (RELU) v = fmaxf(v, 0.f);
        C[(size_t)row * NT + col] = (bf16_t)v;
      }
    }
  }
}

// ---------------- expert GEMM: LDS-free, barrier-free, FT-B -----------------
template <int K, int NT, bool RELU, typename OUT_T>
__global__ __launch_bounds__(256)
void expert_gemm_ft(const bf16_t* __restrict__ A, const bf16_t* __restrict__ Bft,
                    const float* __restrict__ bias, OUT_T* __restrict__ C,
                    const int* __restrict__ offsets) {
  constexpr int nk = K / 32;
  const int e = blockIdx.z;
  const int seg_hi = offsets[e + 1];
  const int blk_row = offsets[e] + blockIdx.y * 128;
  if (blk_row >= seg_hi) return;
  const int wave = threadIdx.x >> 6, lane = threadIdx.x & 63;
  const int row0 = blk_row + wave * 32;
  if (row0 >= seg_hi) return;  // wave-uniform
  const int n0 = blockIdx.x * 64;
  const bf16_t* Ap = A + (size_t)(row0 + (lane & 15)) * K + ((lane >> 4) * 8);
  const bf16_t* Bp = Bft + (size_t)e * NT * K + ((size_t)(n0 >> 4) * nk * 512 + lane * 8);
  f32x4 acc[2][4];
#pragma unroll
  for (int i = 0; i < 2; i++)
#pragma unroll
    for (int j = 0; j < 4; j++) acc[i][j] = (f32x4){0.f, 0.f, 0.f, 0.f};
  bf16x8 aX[2][2], bX[2][4];
#pragma unroll
  for (int mi = 0; mi < 2; mi++) aX[0][mi] = *(const bf16x8*)(Ap + mi * 16 * K);
#pragma unroll
  for (int ni = 0; ni < 4; ni++) bX[0][ni] = *(const bf16x8*)(Bp + (size_t)ni * nk * 512);
#pragma unroll
  for (int kt = 0; kt < nk; kt++) {
    const int cur = kt & 1, nxt = cur ^ 1;
    if (kt + 1 < nk) {
#pragma unroll
      for (int mi = 0; mi < 2; mi++)
        aX[nxt][mi] = *(const bf16x8*)(Ap + mi * 16 * K + (kt + 1) * 32);
#pragma unroll
      for (int ni = 0; ni < 4; ni++)
        bX[nxt][ni] = *(const bf16x8*)(Bp + ((size_t)ni * nk + kt + 1) * 512);
    }
#pragma unroll
    for (int mi = 0; mi < 2; mi++)
#pragma unroll
      for (int ni = 0; ni < 4; ni++)
        acc[mi][ni] = __builtin_amdgcn_mfma_f32_16x16x32_bf16(aX[cur][mi], bX[cur][ni], acc[mi][ni], 0, 0, 0);
  }
  const int fr = lane & 15, q = lane >> 4;
#pragma unroll
  for (int ni = 0; ni < 4; ni++) {
    const int col = n0 + ni * 16 + fr;
    const float bv = bias[e * NT + col];
#pragma unroll
    for (int mi = 0; mi < 2; mi++) {
#pragma unroll
      for (int r = 0; r < 4; r++) {
        const int row = row0 + mi * 16 + q * 4 + r;
        float v = acc[mi][ni][r] + bv;
        if (RELU) v = fmaxf(v, 0.f);
        C[(size_t)row * NT + col] = (OUT_T)v;
      }
    }
  }
}

// ------------------------------ head ---------------------------------------
__global__ __launch_bounds__(256)
void head_kernel(const float* __restrict__ O, const int* __restrict__ a_of,
                 const float* __restrict__ ws_gw, const float* __restrict__ head_W,
                 const float* __restrict__ head_b, float* __restrict__ out) {
  const int b = blockIdx.x, t = threadIdx.x;
  __shared__ float m[512];
  const int a0 = a_of[b * 2], a1 = a_of[b * 2 + 1];
  const float g0 = ws_gw[b * 2], g1 = ws_gw[b * 2 + 1];
  for (int d = t; d < 512; d += 256)
    m[d] = g0 * O[(size_t)a0 * 512 + d] + g1 * O[(size_t)a1 * 512 + d];
  __syncthreads();
  if (t < 160) {
    const int c = t >> 4, ch = t & 15;
    float p = 0.f;
#pragma unroll
    for (int i = 0; i < 32; i++) {
      const int d = i * 16 + ch;
      p += m[d] * head_W[d * 10 + c];
    }
#pragma unroll
    for (int o = 8; o > 0; o >>= 1) p += __shfl_down(p, o, 16);
    if (ch == 0) out[b * 10 + c] = p + head_b[c];
  }
}

// ------------------------------ launch --------------------------------------
extern "C" void kernel_launch(void* const* d_in, const int* in_sizes, int n_in,
                              void* d_out, int out_size, void* d_ws, size_t ws_size,
                              hipStream_t stream) {
  const int* ipc_idx = (const int*)d_in[0];
  const int* role_idx = (const int*)d_in[1];
  const float* bib = (const float*)d_in[2];
  const int* maskp = (const int*)d_in[3];
  const float* ipc_emb = (const float*)d_in[5];
  const float* role_emb = (const float*)d_in[6];
  const float* Wq = (const float*)d_in[7];
  const float* bq = (const float*)d_in[8];
  const float* Wk = (const float*)d_in[9];
  const float* bk = (const float*)d_in[10];
  const float* Wv = (const float*)d_in[11];
  const float* bv = (const float*)d_in[12];
  const float* gc = (const float*)d_in[13];
  const float* ln_g = (const float*)d_in[14];
  const float* ln_b = (const float*)d_in[15];
  const float* gate_W = (const float*)d_in[16];
  const float* gate_b = (const float*)d_in[17];
  const float* exp_b = (const float*)d_in[18];
  const float* W1 = (const float*)d_in[19];
  const float* b1 = (const float*)d_in[20];
  const float* W2 = (const float*)d_in[21];
  const float* b2 = (const float*)d_in[22];
  const float* W3 = (const float*)d_in[23];
  const float* b3 = (const float*)d_in[24];
  const float* head_W = (const float*)d_in[25];
  const float* head_b = (const float*)d_in[26];

  char* ws = (char*)d_ws;
  size_t off = 0;
  auto alloc = [&](size_t bytes) -> char* {
    char* p = ws + off;
    off += (bytes + 255) & ~(size_t)255;
    return p;
  };
  float* kq_qbk = (float*)alloc(257 * 4);
  float* xbar_g = (float*)alloc((size_t)2048 * 256 * 4);
  int* ws_idx = (int*)alloc(4096 * 4);
  float* ws_gw = (float*)alloc(4096 * 4);
  int* list_tok = (int*)alloc(4608 * 4);
  int* a_of = (int*)alloc(4096 * 4);
  int* offs = (int*)alloc(9 * 4);
  bf16_t* W1t = (bf16_t*)alloc((size_t)8 * 1024 * 512 * 2);
  bf16_t* W2t = (bf16_t*)alloc((size_t)8 * 1024 * 1024 * 2);
  bf16_t* W3t = (bf16_t*)alloc((size_t)8 * 512 * 1024 * 2);
  bf16_t* H1c = (bf16_t*)alloc((size_t)4608 * 1024 * 2);
  bf16_t* H2c = (bf16_t*)alloc((size_t)4608 * 1024 * 2);
  float* Oc = (float*)alloc((size_t)4608 * 512 * 4);
  (void)in_sizes; (void)n_in; (void)out_size; (void)ws_size;

  float* out_logits = (float*)d_out;          // [2048*10]
  float* out_idx = (float*)d_out + 20480;     // [2048*2] as float

  transpose_prep<<<dim3(16, 16, 25), 256, 0, stream>>>(W1, W2, W3, W1t, W2t, W3t,
                                                       Wq, bq, Wk, bk, gc, kq_qbk);
  xbar_kernel<<<2048, 256, 0, stream>>>(ipc_idx, role_idx, maskp, ipc_emb, role_emb,
                                        kq_qbk, xbar_g);
  pool_kernel<<<256, 256, 0, stream>>>(xbar_g, Wv, bv, ln_g, ln_b, gate_W, gate_b,
                                       exp_b, out_idx, ws_idx, ws_gw);
  pack_kernel<<<1, 256, 0, stream>>>(ws_idx, list_tok, a_of, offs);
  expert_gemm_g1<1024, true><<<dim3(16, 36, 8), 256, 0, stream>>>(bib, list_tok, W1t, b1, H1c, offs);
  expert_gemm_ft<1024, 1024, true, bf16_t><<<dim3(16, 36, 8), 256, 0, stream>>>(H1c, W2t, b2, H2c, offs);
  expert_gemm_ft<1024, 512, false, float><<<dim3(8, 36, 8), 256, 0, stream>>>(H2c, W3t, b3, Oc, offs);
  head_kernel<<<2048, 256, 0, stream>>>(Oc, a_of, ws_gw, head_W, head_b, out_logits);
}

// Round 3
// 356.252 us; speedup vs baseline: 1.0626x; 1.0385x over previous
//
#include <hip/hip_runtime.h>
#include <hip/hip_bf16.h>
#include <math.h>

// ---------------------------------------------------------------------------
// PatentCitationMoEModule — MI355X implementation, round 9
//  Round 8 (370.0 us) plus:
//   - transpose_prep and xbar MERGED into one dispatch (independent work:
//     BW-bound weight transpose overlaps latency-bound embedding gathers).
//     prep_kq split into a tiny leading dispatch (xbar needs kq).
//   - xbar rewritten branch-free: masked rows gather padding row 0 (zeros)
//     via select, so all 32 row-gathers per wave are in flight at once.
//     Score reduce via LDS transpose (stride-17 pad, conflict-free) instead
//     of 16 serial 6-step shfl chains. Phase-4 re-gather is explicit and
//     branch-free (L2-hot).
//  Fixed harness overhead (ws poison fill + d_in restore) untouched.
// ---------------------------------------------------------------------------

#define LN_EPS 1e-5f

typedef __bf16 bf16_t;
typedef __bf16 bf16x8 __attribute__((ext_vector_type(8)));
typedef float f32x4 __attribute__((ext_vector_type(4)));

struct f4x2 { float4 a, b; };
__device__ __forceinline__ f4x2 ldA8(const float* p) {
  f4x2 v; v.a = *(const float4*)p; v.b = *(const float4*)(p + 4); return v;
}
__device__ __forceinline__ bf16x8 cvt8(const f4x2& v) {
  bf16x8 o;
  o[0] = (bf16_t)v.a.x; o[1] = (bf16_t)v.a.y; o[2] = (bf16_t)v.a.z; o[3] = (bf16_t)v.a.w;
  o[4] = (bf16_t)v.b.x; o[5] = (bf16_t)v.b.y; o[6] = (bf16_t)v.b.z; o[7] = (bf16_t)v.b.w;
  return o;
}

// ----------------------------- prep_kq --------------------------------------
// kq_out[0..255] = Wk @ (gc@Wq + bq);  kq_out[256] = (gc@Wq + bq) . bk
__global__ __launch_bounds__(256)
void prep_kq_kernel(const float* __restrict__ Wq, const float* __restrict__ bq,
                    const float* __restrict__ Wk, const float* __restrict__ bk,
                    const float* __restrict__ gc, float* __restrict__ kq_out) {
  __shared__ float q[256];
  __shared__ float red[4];
  const int t = threadIdx.x, bi = blockIdx.x;
  float s = bq[t];
  for (int d = 0; d < 256; d++) s += gc[d] * Wq[d * 256 + t];
  q[t] = s;
  __syncthreads();
  const int rl = t >> 5, sl = t & 31;
  const int r = bi * 8 + rl;
  float p = 0.f;
#pragma unroll
  for (int i = 0; i < 8; i++) { const int d = sl + 32 * i; p += Wk[r * 256 + d] * q[d]; }
#pragma unroll
  for (int o = 16; o > 0; o >>= 1) p += __shfl_down(p, o, 32);
  if (sl == 0) kq_out[r] = p;
  if (bi == 0) {
    float z2 = q[t] * bk[t];
    const int lane = t & 63, wave = t >> 6;
#pragma unroll
    for (int o = 32; o > 0; o >>= 1) z2 += __shfl_down(z2, o);
    if (lane == 0) red[wave] = z2;
    __syncthreads();
    if (t == 0) kq_out[256] = red[0] + red[1] + red[2] + red[3];
  }
}

// ---------------- merged: xbar (bid<2048) + weight transpose ----------------
// FT-B: frag (nt,kt) = 64 lanes x 8 bf16; lane holds n=nt*16+(lane&15),
// k = kt*32+(lane>>4)*8 .. +7.  Flat elem offset: ((nt*(K/32)+kt)*64+lane)*8.
__global__ __launch_bounds__(256)
void xbar_transpose(const float* __restrict__ W1, const float* __restrict__ W2,
                    const float* __restrict__ W3, bf16_t* __restrict__ B1,
                    bf16_t* __restrict__ B2, bf16_t* __restrict__ B3,
                    const int* __restrict__ ipc_idx, const int* __restrict__ role_idx,
                    const int* __restrict__ maskp,
                    const float* __restrict__ ipc_emb, const float* __restrict__ role_emb,
                    const float* __restrict__ kq_qbk, float* __restrict__ xbar_g) {
  __shared__ __align__(16) float smem[4480];  // 17.9 KB, aliased per path
  const int bid = blockIdx.x;
  const int t = threadIdx.x, lane = t & 63;

  if (bid < 2048) {
    // ================= xbar path =================
    const int b = bid, wave = t >> 6;
    float* sred = smem;                 // [4 waves][64 lanes][17] partials
    float* scores_s = smem + 4352;      // [64]
    float* attn_s = smem + 4416;        // [64]
    const float4 kq = *(const float4*)(kq_qbk + lane * 4);
    const float qbk = kq_qbk[256];
    const int rbase = b * 64 + wave * 16;
    // indices/masks: vectorized uniform loads, kept in registers
    int4 m4[4], i4[4], r4[4];
#pragma unroll
    for (int j = 0; j < 4; j++) {
      m4[j] = *(const int4*)(maskp + rbase + j * 4);
      i4[j] = *(const int4*)(ipc_idx + rbase + j * 4);
      r4[j] = *(const int4*)(role_idx + rbase + j * 4);
    }
    // phase A: branch-free gather (masked -> zero padding row 0) + per-lane dot
#pragma unroll
    for (int i = 0; i < 16; i++) {
      const int mki = (&m4[i / 4].x)[i % 4];
      const int ii = mki ? (&i4[i / 4].x)[i % 4] : 0;
      const int ri = mki ? (&r4[i / 4].x)[i % 4] : 0;
      const float4 xe = *(const float4*)(ipc_emb + (size_t)ii * 256 + lane * 4);
      const float4 re = *(const float4*)(role_emb + (size_t)ri * 256 + lane * 4);
      sred[(wave * 64 + lane) * 17 + i] =
          (xe.x + re.x) * kq.x + (xe.y + re.y) * kq.y +
          (xe.z + re.z) * kq.z + (xe.w + re.w) * kq.w;
    }
    __syncthreads();
    // phase B: per-wave LDS-transpose reduce (each wave reduces its 16 rows)
    {
      const int i_r = lane & 15, g = lane >> 4;
      float s = 0.f;
#pragma unroll
      for (int j = 0; j < 16; j++) s += sred[(wave * 64 + g * 16 + j) * 17 + i_r];
      s += __shfl_xor(s, 16);
      s += __shfl_xor(s, 32);
      const int mval = maskp[rbase + i_r];
      if (lane < 16) scores_s[wave * 16 + lane] = mval ? (s + qbk) : -1e9f;
    }
    __syncthreads();
    // phase C: softmax over 64 scores (wave 0)
    if (wave == 0) {
      const float sv = scores_s[lane];
      float m = sv;
#pragma unroll
      for (int o = 32; o > 0; o >>= 1) m = fmaxf(m, __shfl_xor(m, o));
      const float ev = expf(sv - m);
      float sum = ev;
#pragma unroll
      for (int o = 32; o > 0; o >>= 1) sum += __shfl_xor(sum, o);
      attn_s[lane] = ev / sum;
    }
    __syncthreads();
    // phase D: branch-free re-gather (L2-hot) + attn-weighted sum
    float p0 = 0.f, p1 = 0.f, p2 = 0.f, p3 = 0.f;
#pragma unroll
    for (int i = 0; i < 16; i++) {
      const int mki = (&m4[i / 4].x)[i % 4];
      const int ii = mki ? (&i4[i / 4].x)[i % 4] : 0;
      const int ri = mki ? (&r4[i / 4].x)[i % 4] : 0;
      const float a = attn_s[wave * 16 + i];  // exactly 0 for masked rows
      const float4 xe = *(const float4*)(ipc_emb + (size_t)ii * 256 + lane * 4);
      const float4 re = *(const float4*)(role_emb + (size_t)ri * 256 + lane * 4);
      p0 += a * (xe.x + re.x); p1 += a * (xe.y + re.y);
      p2 += a * (xe.z + re.z); p3 += a * (xe.w + re.w);
    }
    __syncthreads();  // sred region no longer read; reuse as part[4][256]
    *(float4*)&smem[wave * 256 + lane * 4] = make_float4(p0, p1, p2, p3);
    __syncthreads();
    xbar_g[(size_t)b * 256 + t] = smem[t] + smem[256 + t] + smem[512 + t] + smem[768 + t];
    return;
  }

  // ================= transpose path =================
  const int bid2 = bid - 2048;
  const float* W; bf16_t* Bft; int K, N, e, n0, k0;
  if (bid2 < 1024) {            // W1: K=512, N=1024, 128 tiles/expert
    W = W1; Bft = B1; K = 512; N = 1024;
    e = bid2 >> 7; const int r = bid2 & 127;
    n0 = (r & 15) * 64; k0 = (r >> 4) * 64;
  } else if (bid2 < 3072) {     // W2: K=1024, N=1024, 256 tiles/expert
    W = W2; Bft = B2; K = 1024; N = 1024;
    const int q = bid2 - 1024; e = q >> 8; const int r = q & 255;
    n0 = (r & 15) * 64; k0 = (r >> 4) * 64;
  } else {                      // W3: K=1024, N=512, 128 tiles/expert
    W = W3; Bft = B3; K = 1024; N = 512;
    const int q = bid2 - 3072; e = q >> 7; const int r = q & 127;
    n0 = (r & 7) * 64; k0 = (r >> 3) * 64;
  }
  float (*tile)[65] = (float(*)[65])smem;  // 64x65 fits in 4480 floats
  const float* Wp = W + (size_t)e * K * N;
  bf16_t* Bp = Bft + (size_t)e * N * K;
  const int tq = t & 15, th = t >> 4;  // 16 x 16
#pragma unroll
  for (int i = 0; i < 4; i++) {
    const int row = th + 16 * i;  // k-dim
    *(float4*)&tile[row][tq * 4] = *(const float4*)(Wp + (size_t)(k0 + row) * N + n0 + tq * 4);
  }
  __syncthreads();
  const int sub = t >> 6;
  const int nk = K >> 5;
#pragma unroll
  for (int it = 0; it < 2; it++) {
    const int fid = sub + it * 4;            // 8 frag-tiles in a 64x64 tile
    const int ntl = fid & 3, ktl = fid >> 2;
    const int n_l = ntl * 16 + (lane & 15);
    const int k_l = ktl * 32 + (lane >> 4) * 8;
    bf16x8 o;
#pragma unroll
    for (int j = 0; j < 8; j++) o[j] = (bf16_t)tile[k_l + j][n_l];
    const size_t idx = ((((size_t)(n0 >> 4) + ntl) * nk + (k0 >> 5) + ktl) * 64 + lane) * 8;
    *(bf16x8*)(Bp + idx) = o;
  }
}

// ------------- pool: pooled = xbar@Wv + bv, LN, gate, top2 ------------------
// Waves split the d(K)-range so Wv is read once per block (64 MB total).
__global__ __launch_bounds__(256)
void pool_kernel(const float* __restrict__ xbar_g, const float* __restrict__ Wv,
                 const float* __restrict__ bvec,
                 const float* __restrict__ ln_g, const float* __restrict__ ln_b,
                 const float* __restrict__ gate_W, const float* __restrict__ gate_b,
                 const float* __restrict__ expert_biases,
                 float* __restrict__ out_idx_f, int* __restrict__ ws_idx,
                 float* __restrict__ ws_gw) {
  const int rb = blockIdx.x * 8;
  __shared__ __align__(16) float xs[8][256];       // 8 input rows
  __shared__ __align__(16) float pp[4][8][256];    // per-wave d-partials
  const int t = threadIdx.x, wave = t >> 6, lane = t & 63;
  for (int i = t; i < 512; i += 256)
    ((float4*)xs)[i] = ((const float4*)(xbar_g + (size_t)rb * 256))[i];
  __syncthreads();
  f32x4 acc[8];
#pragma unroll
  for (int r = 0; r < 8; r++) acc[r] = (f32x4){0.f, 0.f, 0.f, 0.f};
  const int dbase = wave * 64;
  for (int dd = 0; dd < 64; dd += 4) {
    float4 xr[8];
#pragma unroll
    for (int r = 0; r < 8; r++) xr[r] = *(const float4*)&xs[r][dbase + dd];  // broadcast
#pragma unroll
    for (int j = 0; j < 4; j++) {
      const float4 wv = *(const float4*)(Wv + (size_t)(dbase + dd + j) * 256 + lane * 4);
#pragma unroll
      for (int r = 0; r < 8; r++) {
        const float xv = (&xr[r].x)[j];
        acc[r][0] += xv * wv.x; acc[r][1] += xv * wv.y;
        acc[r][2] += xv * wv.z; acc[r][3] += xv * wv.w;
      }
    }
  }
#pragma unroll
  for (int r = 0; r < 8; r++) *(f32x4*)&pp[wave][r][lane * 4] = acc[r];
  __syncthreads();
  const float4 bvv = *(const float4*)(bvec + lane * 4);
  const float4 lg = *(const float4*)(ln_g + lane * 4);
  const float4 lb = *(const float4*)(ln_b + lane * 4);
#pragma unroll
  for (int rr = 0; rr < 2; rr++) {
    const int r = wave * 2 + rr;
    f32x4 v = *(const f32x4*)&pp[0][r][lane * 4];
#pragma unroll
    for (int w2 = 1; w2 < 4; w2++) {
      const f32x4 qv = *(const f32x4*)&pp[w2][r][lane * 4];
      v[0] += qv[0]; v[1] += qv[1]; v[2] += qv[2]; v[3] += qv[3];
    }
    v[0] += bvv.x; v[1] += bvv.y; v[2] += bvv.z; v[3] += bvv.w;
    float s1 = v[0] + v[1] + v[2] + v[3];
#pragma unroll
    for (int o = 32; o > 0; o >>= 1) s1 += __shfl_xor(s1, o);
    const float mu = s1 * (1.f / 256.f);
    const float4 df = make_float4(v[0] - mu, v[1] - mu, v[2] - mu, v[3] - mu);
    float s2 = df.x * df.x + df.y * df.y + df.z * df.z + df.w * df.w;
#pragma unroll
    for (int o = 32; o > 0; o >>= 1) s2 += __shfl_xor(s2, o);
    const float inv = 1.f / sqrtf(s2 * (1.f / 256.f) + LN_EPS);
    f32x4 rv;
    rv[0] = df.x * inv * lg.x + lb.x; rv[1] = df.y * inv * lg.y + lb.y;
    rv[2] = df.z * inv * lg.z + lb.z; rv[3] = df.w * inv * lg.w + lb.w;
    f32x4 pa = {0.f, 0.f, 0.f, 0.f}, pb = {0.f, 0.f, 0.f, 0.f};
#pragma unroll
    for (int k = 0; k < 4; k++) {
      const int d = lane * 4 + k;
      const f32x4 g0 = *(const f32x4*)(gate_W + d * 8);
      const f32x4 g1 = *(const f32x4*)(gate_W + d * 8 + 4);
      pa += rv[k] * g0;
      pb += rv[k] * g1;
    }
#pragma unroll
    for (int o = 32; o > 0; o >>= 1) {
      pa[0] += __shfl_down(pa[0], o); pa[1] += __shfl_down(pa[1], o);
      pa[2] += __shfl_down(pa[2], o); pa[3] += __shfl_down(pa[3], o);
      pb[0] += __shfl_down(pb[0], o); pb[1] += __shfl_down(pb[1], o);
      pb[2] += __shfl_down(pb[2], o); pb[3] += __shfl_down(pb[3], o);
    }
    if (lane == 0) {
      float aff[8];
#pragma unroll
      for (int j = 0; j < 4; j++) { aff[j] = pa[j] + gate_b[j]; aff[4 + j] = pb[j] + gate_b[4 + j]; }
      float b0 = -1e30f; int i0 = 0;
#pragma unroll
      for (int j = 0; j < 8; j++) {
        const float s = aff[j] + expert_biases[j];
        if (s > b0) { b0 = s; i0 = j; }
      }
      float b1v = -1e30f; int i1 = 0;
#pragma unroll
      for (int j = 0; j < 8; j++) {
        const float s = aff[j] + expert_biases[j];
        if (j != i0 && s > b1v) { b1v = s; i1 = j; }
      }
      const float a0 = aff[i0], a1 = aff[i1];
      const float m = fmaxf(a0, a1);
      const float e0 = expf(a0 - m), e1 = expf(a1 - m);
      const float invs = 1.f / (e0 + e1);
      const int bg = rb + r;
      ws_idx[bg * 2] = i0; ws_idx[bg * 2 + 1] = i1;
      ws_gw[bg * 2] = e0 * invs; ws_gw[bg * 2 + 1] = e1 * invs;
      out_idx_f[bg * 2] = (float)i0; out_idx_f[bg * 2 + 1] = (float)i1;
    }
  }
}

// ------------------------ pack (64-aligned segments) ------------------------
__global__ __launch_bounds__(256)
void pack_kernel(const int* __restrict__ ws_idx, int* __restrict__ list_token,
                 int* __restrict__ a_of, int* __restrict__ offsets_g) {
  __shared__ int cnt[8]; __shared__ int off[9]; __shared__ int fill[8];
  const int t = threadIdx.x;
  if (t < 8) cnt[t] = 0;
  __syncthreads();
  for (int a = t; a < 4096; a += 256) atomicAdd(&cnt[ws_idx[a]], 1);
  __syncthreads();
  if (t == 0) {
    off[0] = 0;
    for (int e = 0; e < 8; e++) off[e + 1] = off[e] + ((cnt[e] + 63) & ~63);
  }
  __syncthreads();
  if (t < 8) fill[t] = off[t];
  if (t < 9) offsets_g[t] = off[t];
  for (int a = t; a < 4608; a += 256) list_token[a] = 0;  // pad rows -> token 0
  __syncthreads();
  for (int a = t; a < 4096; a += 256) {
    const int e = ws_idx[a];
    const int pos = atomicAdd(&fill[e], 1);
    list_token[pos] = a >> 1;
    a_of[a] = pos;
  }
}

// --------- GEMM-1: fused bib gather (fp32->bf16 in-register), FT-B ----------
// C[rows,NT] = cvt_bf16(bib[list_token[row]]) @ B1_e ; K=512.
template <int NT, bool RELU>
__global__ __launch_bounds__(256)
void expert_gemm_g1(const float* __restrict__ bib, const int* __restrict__ list_token,
                    const bf16_t* __restrict__ Bft, const float* __restrict__ bias,
                    bf16_t* __restrict__ C, const int* __restrict__ offsets) {
  constexpr int K = 512, nk = K / 32;
  const int e = blockIdx.z;
  const int seg_hi = offsets[e + 1];
  const int blk_row = offsets[e] + blockIdx.y * 128;
  if (blk_row >= seg_hi) return;
  const int wave = threadIdx.x >> 6, lane = threadIdx.x & 63;
  const int row0 = blk_row + wave * 32;
  if (row0 >= seg_hi) return;
  const int n0 = blockIdx.x * 64;
  const int tok0 = list_token[row0 + (lane & 15)];
  const int tok1 = list_token[row0 + 16 + (lane & 15)];
  const float* Ap0 = bib + (size_t)tok0 * 512 + (lane >> 4) * 8;
  const float* Ap1 = bib + (size_t)tok1 * 512 + (lane >> 4) * 8;
  const bf16_t* Bp = Bft + (size_t)e * NT * K + ((size_t)(n0 >> 4) * nk * 512 + lane * 8);
  f32x4 acc[2][4];
#pragma unroll
  for (int i = 0; i < 2; i++)
#pragma unroll
    for (int j = 0; j < 4; j++) acc[i][j] = (f32x4){0.f, 0.f, 0.f, 0.f};
  f4x2 aS[2][2]; bf16x8 bX[2][4];
  aS[0][0] = ldA8(Ap0); aS[0][1] = ldA8(Ap1);
#pragma unroll
  for (int ni = 0; ni < 4; ni++) bX[0][ni] = *(const bf16x8*)(Bp + (size_t)ni * nk * 512);
#pragma unroll
  for (int kt = 0; kt < nk; kt++) {
    const int cur = kt & 1, nxt = cur ^ 1;
    if (kt + 1 < nk) {
      aS[nxt][0] = ldA8(Ap0 + (kt + 1) * 32);
      aS[nxt][1] = ldA8(Ap1 + (kt + 1) * 32);
#pragma unroll
      for (int ni = 0; ni < 4; ni++)
        bX[nxt][ni] = *(const bf16x8*)(Bp + ((size_t)ni * nk + kt + 1) * 512);
    }
    const bf16x8 a0 = cvt8(aS[cur][0]), a1 = cvt8(aS[cur][1]);
#pragma unroll
    for (int ni = 0; ni < 4; ni++) {
      acc[0][ni] = __builtin_amdgcn_mfma_f32_16x16x32_bf16(a0, bX[cur][ni], acc[0][ni], 0, 0, 0);
      acc[1][ni] = __builtin_amdgcn_mfma_f32_16x16x32_bf16(a1, bX[cur][ni], acc[1][ni], 0, 0, 0);
    }
  }
  const int fr = lane & 15, q = lane >> 4;
#pragma unroll
  for (int ni = 0; ni < 4; ni++) {
    const int col = n0 + ni * 16 + fr;
    const float bv = bias[e * NT + col];
#pragma unroll
    for (int mi = 0; mi < 2; mi++) {
#pragma unroll
      for (int r = 0; r < 4; r++) {
        const int row = row0 + mi * 16 + q * 4 + r;
        float v = acc[mi][ni][r] + bv;
        if (RELU) v = fmaxf(v, 0.f);
        C[(size_t)row * NT + col] = (bf16_t)v;
      }
    }
  }
}

// ---------------- expert GEMM: LDS-free, barrier-free, FT-B -----------------
template <int K, int NT, bool RELU, typename OUT_T>
__global__ __launch_bounds__(256)
void expert_gemm_ft(const bf16_t* __restrict__ A, const bf16_t* __restrict__ Bft,
                    const float* __restrict__ bias, OUT_T* __restrict__ C,
                    const int* __restrict__ offsets) {
  constexpr int nk = K / 32;
  const int e = blockIdx.z;
  const int seg_hi = offsets[e + 1];
  const int blk_row = offsets[e] + blockIdx.y * 128;
  if (blk_row >= seg_hi) return;
  const int wave = threadIdx.x >> 6, lane = threadIdx.x & 63;
  const int row0 = blk_row + wave * 32;
  if (row0 >= seg_hi) return;  // wave-uniform
  const int n0 = blockIdx.x * 64;
  const bf16_t* Ap = A + (size_t)(row0 + (lane & 15)) * K + ((lane >> 4) * 8);
  const bf16_t* Bp = Bft + (size_t)e * NT * K + ((size_t)(n0 >> 4) * nk * 512 + lane * 8);
  f32x4 acc[2][4];
#pragma unroll
  for (int i = 0; i < 2; i++)
#pragma unroll
    for (int j = 0; j < 4; j++) acc[i][j] = (f32x4){0.f, 0.f, 0.f, 0.f};
  bf16x8 aX[2][2], bX[2][4];
#pragma unroll
  for (int mi = 0; mi < 2; mi++) aX[0][mi] = *(const bf16x8*)(Ap + mi * 16 * K);
#pragma unroll
  for (int ni = 0; ni < 4; ni++) bX[0][ni] = *(const bf16x8*)(Bp + (size_t)ni * nk * 512);
#pragma unroll
  for (int kt = 0; kt < nk; kt++) {
    const int cur = kt & 1, nxt = cur ^ 1;
    if (kt + 1 < nk) {
#pragma unroll
      for (int mi = 0; mi < 2; mi++)
        aX[nxt][mi] = *(const bf16x8*)(Ap + mi * 16 * K + (kt + 1) * 32);
#pragma unroll
      for (int ni = 0; ni < 4; ni++)
        bX[nxt][ni] = *(const bf16x8*)(Bp + ((size_t)ni * nk + kt + 1) * 512);
    }
#pragma unroll
    for (int mi = 0; mi < 2; mi++)
#pragma unroll
      for (int ni = 0; ni < 4; ni++)
        acc[mi][ni] = __builtin_amdgcn_mfma_f32_16x16x32_bf16(aX[cur][mi], bX[cur][ni], acc[mi][ni], 0, 0, 0);
  }
  const int fr = lane & 15, q = lane >> 4;
#pragma unroll
  for (int ni = 0; ni < 4; ni++) {
    const int col = n0 + ni * 16 + fr;
    const float bv = bias[e * NT + col];
#pragma unroll
    for (int mi = 0; mi < 2; mi++) {
#pragma unroll
      for (int r = 0; r < 4; r++) {
        const int row = row0 + mi * 16 + q * 4 + r;
        float v = acc[mi][ni][r] + bv;
        if (RELU) v = fmaxf(v, 0.f);
        C[(size_t)row * NT + col] = (OUT_T)v;
      }
    }
  }
}

// ------------------------------ head ---------------------------------------
__global__ __launch_bounds__(256)
void head_kernel(const float* __restrict__ O, const int* __restrict__ a_of,
                 const float* __restrict__ ws_gw, const float* __restrict__ head_W,
                 const float* __restrict__ head_b, float* __restrict__ out) {
  const int b = blockIdx.x, t = threadIdx.x;
  __shared__ float m[512];
  const int a0 = a_of[b * 2], a1 = a_of[b * 2 + 1];
  const float g0 = ws_gw[b * 2], g1 = ws_gw[b * 2 + 1];
  for (int d = t; d < 512; d += 256)
    m[d] = g0 * O[(size_t)a0 * 512 + d] + g1 * O[(size_t)a1 * 512 + d];
  __syncthreads();
  if (t < 160) {
    const int c = t >> 4, ch = t & 15;
    float p = 0.f;
#pragma unroll
    for (int i = 0; i < 32; i++) {
      const int d = i * 16 + ch;
      p += m[d] * head_W[d * 10 + c];
    }
#pragma unroll
    for (int o = 8; o > 0; o >>= 1) p += __shfl_down(p, o, 16);
    if (ch == 0) out[b * 10 + c] = p + head_b[c];
  }
}

// ------------------------------ launch --------------------------------------
extern "C" void kernel_launch(void* const* d_in, const int* in_sizes, int n_in,
                              void* d_out, int out_size, void* d_ws, size_t ws_size,
                              hipStream_t stream) {
  const int* ipc_idx = (const int*)d_in[0];
  const int* role_idx = (const int*)d_in[1];
  const float* bib = (const float*)d_in[2];
  const int* maskp = (const int*)d_in[3];
  const float* ipc_emb = (const float*)d_in[5];
  const float* role_emb = (const float*)d_in[6];
  const float* Wq = (const float*)d_in[7];
  const float* bq = (const float*)d_in[8];
  const float* Wk = (const float*)d_in[9];
  const float* bk = (const float*)d_in[10];
  const float* Wv = (const float*)d_in[11];
  const float* bv = (const float*)d_in[12];
  const float* gc = (const float*)d_in[13];
  const float* ln_g = (const float*)d_in[14];
  const float* ln_b = (const float*)d_in[15];
  const float* gate_W = (const float*)d_in[16];
  const float* gate_b = (const float*)d_in[17];
  const float* exp_b = (const float*)d_in[18];
  const float* W1 = (const float*)d_in[19];
  const float* b1 = (const float*)d_in[20];
  const float* W2 = (const float*)d_in[21];
  const float* b2 = (const float*)d_in[22];
  const float* W3 = (const float*)d_in[23];
  const float* b3 = (const float*)d_in[24];
  const float* head_W = (const float*)d_in[25];
  const float* head_b = (const float*)d_in[26];

  char* ws = (char*)d_ws;
  size_t off = 0;
  auto alloc = [&](size_t bytes) -> char* {
    char* p = ws + off;
    off += (bytes + 255) & ~(size_t)255;
    return p;
  };
  float* kq_qbk = (float*)alloc(257 * 4);
  float* xbar_g = (float*)alloc((size_t)2048 * 256 * 4);
  int* ws_idx = (int*)alloc(4096 * 4);
  float* ws_gw = (float*)alloc(4096 * 4);
  int* list_tok = (int*)alloc(4608 * 4);
  int* a_of = (int*)alloc(4096 * 4);
  int* offs = (int*)alloc(9 * 4);
  bf16_t* W1t = (bf16_t*)alloc((size_t)8 * 1024 * 512 * 2);
  bf16_t* W2t = (bf16_t*)alloc((size_t)8 * 1024 * 1024 * 2);
  bf16_t* W3t = (bf16_t*)alloc((size_t)8 * 512 * 1024 * 2);
  bf16_t* H1c = (bf16_t*)alloc((size_t)4608 * 1024 * 2);
  bf16_t* H2c = (bf16_t*)alloc((size_t)4608 * 1024 * 2);
  float* Oc = (float*)alloc((size_t)4608 * 512 * 4);
  (void)in_sizes; (void)n_in; (void)out_size; (void)ws_size;

  float* out_logits = (float*)d_out;          // [2048*10]
  float* out_idx = (float*)d_out + 20480;     // [2048*2] as float

  prep_kq_kernel<<<32, 256, 0, stream>>>(Wq, bq, Wk, bk, gc, kq_qbk);
  // 2048 xbar blocks + 4096 transpose tiles (W1:1024, W2:2048, W3:1024)
  xbar_transpose<<<6144, 256, 0, stream>>>(W1, W2, W3, W1t, W2t, W3t,
                                           ipc_idx, role_idx, maskp,
                                           ipc_emb, role_emb, kq_qbk, xbar_g);
  pool_kernel<<<256, 256, 0, stream>>>(xbar_g, Wv, bv, ln_g, ln_b, gate_W, gate_b,
                                       exp_b, out_idx, ws_idx, ws_gw);
  pack_kernel<<<1, 256, 0, stream>>>(ws_idx, list_tok, a_of, offs);
  expert_gemm_g1<1024, true><<<dim3(16, 36, 8), 256, 0, stream>>>(bib, list_tok, W1t, b1, H1c, offs);
  expert_gemm_ft<1024, 1024, true, bf16_t><<<dim3(16, 36, 8), 256, 0, stream>>>(H1c, W2t, b2, H2c, offs);
  expert_gemm_ft<1024, 512, false, float><<<dim3(8, 36, 8), 256, 0, stream>>>(H2c, W3t, b3, Oc, offs);
  head_kernel<<<2048, 256, 0, stream>>>(Oc, a_of, ws_gw, head_W, head_b, out_logits);
}